// Round 1
// 193.350 us; speedup vs baseline: 1.0200x; 1.0200x over previous
//
#include <hip/hip_runtime.h>
#include <math.h>

// Problem constants (from reference): S=7, NB=2, C=20
#define SS 7
#define CC 20
#define CELL_PRED 30            // C + NB*5  (120 B/cell)
#define CELL_TGT  25            // C + 1 + 4 (100 B/cell)
#define GRID 1024               // partials fit the known-good 4 KB workspace
#define TPB 64                  // ONE wave per block: no __syncthreads anywhere
#define REDUCE_BLOCK 256

// R6 theory: R5's direct-load version is TA/L1 transaction-bound, not BW-bound
// (VALUBusy 5.7%, HBM 20%, 0 conflicts). 40 strided VMEM instrs/cell x 64
// distinct cache lines each ~= 52 us of pure address processing. Fix: wave-
// private LDS staging via global_load_lds (16 contiguous 1KB/256B DMA issues
// per 64-cell tile), double-buffered, counted s_waitcnt vmcnt(16) -- no
// barrier, no vmcnt(0) in the steady loop, so outstanding bytes never drain
// (the R5 cliff was a block-tile + __syncthreads artifact).
//
// Tile geometry: 64 cells/wave-tile.
//   pred slab: 64*120 = 7680 B  -> 7x width-16 issues + 2x width-4 issues
//   tgt  slab: 64*100 = 6400 B  -> 6x width-16 issues + 1x width-4 issue
//   16 DMA issues/tile, LDS 2*14080 = 28160 B/block -> 5 blocks/CU max.

#define PRED_TILE_B 7680
#define TGT_TILE_B  6400
#define TILE_FLOATS 3520        // (7680+6400)/4

__device__ __forceinline__ void stage_tile(const float* __restrict__ pred,
                                           const float* __restrict__ tgt,
                                           size_t t, float* lbuf, int lane)
{
    const char* gp = (const char*)pred + t * (size_t)PRED_TILE_B;
    const char* gt = (const char*)tgt  + t * (size_t)TGT_TILE_B;
    char* lp = (char*)lbuf;
    // LDS dest is wave-uniform base; HW adds lane*width. Global src is per-lane.
    #pragma unroll
    for (int k = 0; k < 7; ++k)
        __builtin_amdgcn_global_load_lds((const float*)(gp + k * 1024 + lane * 16),
                                         (float*)(lp + k * 1024), 16, 0, 0);
    #pragma unroll
    for (int k = 0; k < 2; ++k)
        __builtin_amdgcn_global_load_lds((const float*)(gp + 7168 + k * 256 + lane * 4),
                                         (float*)(lp + 7168 + k * 256), 4, 0, 0);
    #pragma unroll
    for (int k = 0; k < 6; ++k)
        __builtin_amdgcn_global_load_lds((const float*)(gt + k * 1024 + lane * 16),
                                         (float*)(lp + PRED_TILE_B + k * 1024), 16, 0, 0);
    __builtin_amdgcn_global_load_lds((const float*)(gt + 6144 + lane * 4),
                                     (float*)(lp + PRED_TILE_B + 6144), 4, 0, 0);
}

// Shared math body: pc = this cell's 30 pred floats (8B-aligned in both LDS and
// global paths), tc = this cell's 25 tgt floats. Pointer provenance lets the
// compiler emit ds_read_* for the LDS call site and global_load_* for the tail.
__device__ __forceinline__ float cell_loss_ptr(const float* __restrict__ pc,
                                               const float* __restrict__ tc) {
    const float EPS = 1e-6f;
    float tv[CELL_TGT];
    #pragma unroll
    for (int j = 0; j < CELL_TGT; ++j) tv[j] = tc[j];

    const float2* p2 = (const float2*)pc;
    float cls = 0.0f;
    #pragma unroll
    for (int j = 0; j < 10; ++j) {
        float2 v = p2[j];
        float d0 = v.x - tv[2 * j];
        float d1 = v.y - tv[2 * j + 1];
        cls += d0 * d0;
        cls += d1 * d1;
    }
    float b[10];
    #pragma unroll
    for (int j = 0; j < 5; ++j) {
        float2 v = p2[10 + j];
        b[2 * j] = v.x; b[2 * j + 1] = v.y;
    }
    const float* b1 = b;        // pred[20..24]
    const float* b2 = b + 5;    // pred[25..29]
    const float* tb = tv + CC;  // tgt[20..24]

    float obj = (tb[0] == 1.0f) ? 1.0f : 0.0f;

    float t_x1 = tb[0] - tb[2] * 0.5f, t_y1 = tb[1] - tb[3] * 0.5f;
    float t_x2 = tb[0] + tb[2] * 0.5f, t_y2 = tb[1] + tb[3] * 0.5f;
    float t_area = fabsf((t_x2 - t_x1) * (t_y2 - t_y1));

    float a_x1 = b1[0] - b1[2] * 0.5f, a_y1 = b1[1] - b1[3] * 0.5f;
    float a_x2 = b1[0] + b1[2] * 0.5f, a_y2 = b1[1] + b1[3] * 0.5f;
    float iw1 = fmaxf(fminf(a_x2, t_x2) - fmaxf(a_x1, t_x1), 0.0f);
    float ih1 = fmaxf(fminf(a_y2, t_y2) - fmaxf(a_y1, t_y1), 0.0f);
    float inter1 = iw1 * ih1;
    float area1 = fabsf((a_x2 - a_x1) * (a_y2 - a_y1));
    float iou1 = inter1 / (area1 + t_area - inter1 + EPS);

    float c_x1 = b2[0] - b2[2] * 0.5f, c_y1 = b2[1] - b2[3] * 0.5f;
    float c_x2 = b2[0] + b2[2] * 0.5f, c_y2 = b2[1] + b2[3] * 0.5f;
    float iw2 = fmaxf(fminf(c_x2, t_x2) - fmaxf(c_x1, t_x1), 0.0f);
    float ih2 = fmaxf(fminf(c_y2, t_y2) - fmaxf(c_y1, t_y1), 0.0f);
    float inter2 = iw2 * ih2;
    float area2 = fabsf((c_x2 - c_x1) * (c_y2 - c_y1));
    float iou2 = inter2 / (area2 + t_area - inter2 + EPS);

    bool pick1 = iou1 > iou2;
    float r0 = pick1 ? b1[0] : b2[0];
    float r1 = pick1 ? b1[1] : b2[1];
    float r2 = pick1 ? b1[2] : b2[2];
    float r3 = pick1 ? b1[3] : b2[3];
    float r4 = pick1 ? b1[4] : b2[4];

    float dx = r0 - tb[0], dy = r1 - tb[1];
    float xy = dx * dx + dy * dy;
    float dw = sqrtf(r2) - sqrtf(tb[2]);
    float dh = sqrtf(r3) - sqrtf(tb[3]);
    float wh = dw * dw + dh * dh;
    float coord = 5.0f * (xy + wh);
    float dconf = r4 - tb[4];
    float conf = dconf * dconf;

    float noobj = 0.5f * (1.0f - obj) * (b1[4] * b1[4] + b2[4] * b2[4]);
    return obj * (coord + conf + cls) + noobj;
}

__global__ __launch_bounds__(TPB) void yolo_stream(
    const float* __restrict__ pred,
    const float* __restrict__ tgt,
    float* __restrict__ partials,     // [GRID]
    int nCells)
{
    __shared__ __align__(16) float lds[2][TILE_FLOATS];
    const int lane = threadIdx.x;         // 0..63, one wave per block
    const int bid  = blockIdx.x;
    const int nTiles = nCells >> 6;

    float loss = 0.0f;
    const int myT = (bid < nTiles) ? ((nTiles - bid - 1) / GRID + 1) : 0;

    if (myT > 0) {
        float* bufA = lds[0];
        float* bufB = lds[1];
        size_t t = (size_t)bid;
        stage_tile(pred, tgt, t, bufA, lane);          // prologue: 16 issues
        for (int i = 0; i < myT; ++i) {
            // keep this iter's ds_reads from sinking below next iter's DMA
            asm volatile("" ::: "memory");
            if (i + 1 < myT) {
                stage_tile(pred, tgt, t + GRID, bufB, lane);   // 16 issues
                // wait for the OLDER 16 (current tile); next tile stays in
                // flight across the whole compute phase -> no drain cliff.
                asm volatile("s_waitcnt vmcnt(16)" ::: "memory");
            } else {
                asm volatile("s_waitcnt vmcnt(0)" ::: "memory");
            }
            loss += cell_loss_ptr(bufA + lane * CELL_PRED,
                                  bufA + (PRED_TILE_B / 4) + lane * CELL_TGT);
            float* tmp = bufA; bufA = bufB; bufB = tmp;
            t += GRID;
        }
    }

    // ragged tail (nCells % 64 != 0; zero for N=16384): direct global path
    if (bid == 0) {
        for (int c = (nTiles << 6) + lane; c < nCells; c += TPB)
            loss += cell_loss_ptr(pred + (size_t)c * CELL_PRED,
                                  tgt  + (size_t)c * CELL_TGT);
    }

    // single-wave butterfly, one store per block
    #pragma unroll
    for (int off = 32; off > 0; off >>= 1)
        loss += __shfl_down(loss, off, 64);
    if (lane == 0) partials[bid] = loss;
}

__global__ __launch_bounds__(REDUCE_BLOCK) void yolo_final_reduce(
    const float* __restrict__ partials, int nPartials, double invN,
    float* __restrict__ out)
{
    __shared__ double s_red[4];
    const float4* p4 = (const float4*)partials;   // d_ws is 16-aligned
    double sum = 0.0;
    for (int i = threadIdx.x; i < (nPartials >> 2); i += REDUCE_BLOCK) {
        float4 v = p4[i];
        sum += (double)v.x + (double)v.y + (double)v.z + (double)v.w;
    }
    for (int i = ((nPartials >> 2) << 2) + threadIdx.x; i < nPartials; i += REDUCE_BLOCK)
        sum += (double)partials[i];
    #pragma unroll
    for (int off = 32; off > 0; off >>= 1)
        sum += __shfl_down(sum, off, 64);
    if ((threadIdx.x & 63) == 0) s_red[threadIdx.x >> 6] = sum;
    __syncthreads();
    if (threadIdx.x == 0) {
        double s = (s_red[0] + s_red[1]) + (s_red[2] + s_red[3]);
        out[0] = (float)(s * invN);
    }
}

extern "C" void kernel_launch(void* const* d_in, const int* in_sizes, int n_in,
                              void* d_out, int out_size, void* d_ws, size_t ws_size,
                              hipStream_t stream) {
    const float* pred = (const float*)d_in[0];
    const float* tgt  = (const float*)d_in[1];
    float* out = (float*)d_out;
    float* partials = (float*)d_ws;

    const int N = in_sizes[0] / (SS * SS * CELL_PRED);   // 16384
    const int nCells = N * SS * SS;                      // 802816

    yolo_stream<<<GRID, TPB, 0, stream>>>(pred, tgt, partials, nCells);
    yolo_final_reduce<<<1, REDUCE_BLOCK, 0, stream>>>(partials, GRID, 1.0 / (double)N, out);
}